// Round 9
// baseline (608.434 us; speedup 1.0000x reference)
//
#include <hip/hip_runtime.h>
#include <hip/hip_bf16.h>

typedef unsigned short u16;
typedef unsigned int u32;

#define N_NODES 50000
#define N_EDGES 800000
#define DHID 256
#define NCHUNK 49       // ceil(50000/1024)
#define PADCAP (1 << 20)  // padded CSR capacity (entries); >= E + 3*Nn = 950k

typedef __attribute__((ext_vector_type(8))) _Float16 f16x8;
typedef __attribute__((ext_vector_type(4))) float f32x4;
typedef __attribute__((ext_vector_type(2))) float f32x2;

// ---------- helpers ----------
__device__ __forceinline__ u16 f2bf(float f) {
    u32 u = __float_as_uint(f);
    u32 r = (u + 0x7FFFu + ((u >> 16) & 1u)) >> 16;
    return (u16)r;
}
__device__ __forceinline__ u16 f2h(float f) {
    _Float16 h = (_Float16)f;
    union { _Float16 h; u16 u; } c; c.h = h;
    return c.u;
}
__device__ __forceinline__ void gl_lds16(const void* g, void* l) {
    __builtin_amdgcn_global_load_lds(
        (const __attribute__((address_space(1))) u32*)g,
        (__attribute__((address_space(3))) u32*)l, 16, 0, 0);
}

// ---------- fused prep: x->f16, zero deg/hist/tile-zero-rows, W->W^T f16, pad-fill ----
#define SPLIT_BLKS 12500
#define ZERO_BLKS 196
#define W_BLKS 512
#define PF_BLKS 512  // PADCAP/8 threads / 256
__global__ void prep_fused(const float* __restrict__ x, u16* __restrict__ xf,
                           const float* __restrict__ W1, const float* __restrict__ W2,
                           u16* __restrict__ W1t, u16* __restrict__ W2t,
                           int* __restrict__ deg, int* __restrict__ hist,
                           u32* __restrict__ hs32, u16* __restrict__ col16p) {
    const int b = blockIdx.x, tid = threadIdx.x;
    if (b < SPLIT_BLKS) {
        int i = b * 256 + tid;  // n4 = 3.2M exact
        float4 v = ((const float4*)x)[i];
        u16 h0 = f2h(v.x), h1 = f2h(v.y), h2 = f2h(v.z), h3 = f2h(v.w);
        uint2 hv;
        hv.x = (u32)h0 | ((u32)h1 << 16);
        hv.y = (u32)h2 | ((u32)h3 << 16);
        ((uint2*)xf)[i] = hv;
    } else if (b < SPLIT_BLKS + ZERO_BLKS) {
        int j = (b - SPLIT_BLKS) * 256 + tid;
        if (j < N_NODES) deg[j] = 0;
        if (j < 128) {  // zero row Nn of each of the 8 tiles (64 B each)
            int t = j >> 4, w = j & 15;
            hs32[((size_t)t * (N_NODES + 1) + N_NODES) * 16 + w] = 0;
        }
        if (j < 64) hist[j] = 0;
    } else if (b < SPLIT_BLKS + ZERO_BLKS + W_BLKS) {
        int idx = b - (SPLIT_BLKS + ZERO_BLKS);  // 0..511
        int y = idx >> 8, n = idx & 255, k = tid;
        const float* W = y ? W2 : W1;
        u16* o = y ? W2t : W1t;
        o[n * 256 + k] = f2h(W[k * 256 + n]);
    } else {
        // pre-fill padded CSR with zero-row index N_NODES (8 entries / thread)
        int j = (b - (SPLIT_BLKS + ZERO_BLKS + W_BLKS)) * 256 + tid;
        const u32 pat = (u32)N_NODES | ((u32)N_NODES << 16);
        uint4 w; w.x = pat; w.y = pat; w.z = pat; w.w = pat;
        ((uint4*)col16p)[j] = w;
    }
}

__global__ void deg_kernel(const int* __restrict__ dst, int* __restrict__ deg, int E) {
    int e = blockIdx.x * 256 + threadIdx.x;
    if (e < E) atomicAdd(&deg[dst[e]], 1);
}

// ---------- counting sort by degree (64 bins) ----------
__global__ void hist_kernel(const int* __restrict__ deg, int* __restrict__ hist, int n) {
    int i = blockIdx.x * 256 + threadIdx.x;
    if (i < n) atomicAdd(&hist[min(deg[i], 63)], 1);
}
__global__ void binscan_kernel(int* __restrict__ hist, int* __restrict__ bincur) {
    const int l = threadIdx.x & 63;
    int v = hist[l];
    int x = v;
#pragma unroll
    for (int off = 1; off < 64; off <<= 1) {
        int t = __shfl_up(x, off, 64);
        if (l >= off) x += t;
    }
    bincur[l] = x - v;
}
__global__ void scatter_kernel(const int* __restrict__ deg, int* __restrict__ bincur,
                               int* __restrict__ perm, int n) {
    int i = blockIdx.x * 256 + threadIdx.x;
    if (i < n) {
        int pos = atomicAdd(&bincur[min(deg[i], 63)], 1);
        perm[pos] = i;
    }
}

// ---------- padded-CSR scans: counts padded to x4 ----------
__global__ __launch_bounds__(1024) void scan1_kernel(const int* __restrict__ deg,
                                                     int* __restrict__ partial,
                                                     int* __restrict__ totals, int n) {
    __shared__ int wsum[16];
    __shared__ int woff[16];
    const int tid = threadIdx.x, lane = tid & 63, wid = tid >> 6;
    const int idx = blockIdx.x * 1024 + tid;
    int v = (idx < n) ? ((deg[idx] + 3) & ~3) : 0;
    int x = v;
#pragma unroll
    for (int off = 1; off < 64; off <<= 1) {
        int t = __shfl_up(x, off, 64);
        if (lane >= off) x += t;
    }
    if (lane == 63) wsum[wid] = x;
    __syncthreads();
    if (tid == 0) {
        int s = 0;
#pragma unroll
        for (int w = 0; w < 16; ++w) { woff[w] = s; s += wsum[w]; }
    }
    __syncthreads();
    x += woff[wid];
    partial[idx] = x;
    if (tid == 1023) totals[blockIdx.x] = x;
}

__global__ void scan3_kernel(const int* __restrict__ deg, const int* __restrict__ partial,
                             const int* __restrict__ totals, int* __restrict__ rp4,
                             int* __restrict__ cursor, int n) {
    __shared__ int coff_s;
    const int tid = threadIdx.x;
    const int mychunk = blockIdx.x >> 2;
    if (tid < 64) {
        int v = (tid < NCHUNK) ? totals[tid] : 0;
        int x = v;
#pragma unroll
        for (int off = 1; off < 64; off <<= 1) {
            int t = __shfl_up(x, off, 64);
            if (tid >= off) x += t;
        }
        if (tid == mychunk) coff_s = x - v;
    }
    __syncthreads();
    int i = blockIdx.x * 256 + tid;
    if (i < n) {
        int pv = (deg[i] + 3) & ~3;
        int e = coff_s + partial[i] - pv;
        rp4[i] = e;
        cursor[i] = e;
    }
}

__global__ void fill_kernel(const int* __restrict__ src, const int* __restrict__ dst,
                            int* __restrict__ cursor, u16* __restrict__ col16p, int E) {
    int e = blockIdx.x * 256 + threadIdx.x;
    if (e < E) {
        int p = atomicAdd(&cursor[dst[e]], 1);
        col16p[p] = (u16)src[e];
    }
}

// ---------- GEMM (f16): hs = (A @ W) * rsqrt(deg[row]+1), bf16 TILE-MAJOR out ----------
__global__ __launch_bounds__(256) void gemm_f16_kernel(
    const u16* __restrict__ Af, const u16* __restrict__ Bt,
    const int* __restrict__ deg, u16* __restrict__ out, int M) {
    __shared__ u16 As[128 * 32];
    __shared__ u16 Bs[128 * 32];
    const int tid = threadIdx.x;
    const int wave = tid >> 6;
    const int lane = tid & 63;
    const int wm = wave >> 1, wn = wave & 1;
    const int quad = lane >> 4, l16 = lane & 15;
    const int m0 = blockIdx.x * 128;
    const int n0 = blockIdx.y * 128;

    f32x4 acc[4][4] = {};

    const int row0 = tid >> 2, row1 = (256 + tid) >> 2;
    const int kk = (tid & 3) * 8;
    int ar0 = m0 + row0; if (ar0 >= M) ar0 = M - 1;
    int ar1 = m0 + row1; if (ar1 >= M) ar1 = M - 1;
    const size_t aoff0 = (size_t)ar0 * 256 + kk;
    const size_t aoff1 = (size_t)ar1 * 256 + kk;
    const size_t boff0 = (size_t)(n0 + row0) * 256 + kk;
    const size_t boff1 = (size_t)(n0 + row1) * 256 + kk;
    const size_t l0 = (size_t)(wave * 64) * 8;
    const size_t l1 = (size_t)(256 + wave * 64) * 8;

    for (int ko = 0; ko < 8; ++ko) {
        const int koff = ko * 32;
        __syncthreads();
        gl_lds16(Af + aoff0 + koff, &As[l0]);
        gl_lds16(Af + aoff1 + koff, &As[l1]);
        gl_lds16(Bt + boff0 + koff, &Bs[l0]);
        gl_lds16(Bt + boff1 + koff, &Bs[l1]);
        asm volatile("s_waitcnt vmcnt(0)" ::: "memory");
        __syncthreads();

        f16x8 af[4], bf[4];
#pragma unroll
        for (int mi = 0; mi < 4; ++mi)
            af[mi] = *(const f16x8*)&As[(wm * 64 + mi * 16 + l16) * 32 + quad * 8];
#pragma unroll
        for (int ni = 0; ni < 4; ++ni)
            bf[ni] = *(const f16x8*)&Bs[(wn * 64 + ni * 16 + l16) * 32 + quad * 8];
#pragma unroll
        for (int mi = 0; mi < 4; ++mi)
#pragma unroll
            for (int ni = 0; ni < 4; ++ni)
                acc[mi][ni] = __builtin_amdgcn_mfma_f32_16x16x32_f16(af[mi], bf[ni], acc[mi][ni], 0, 0, 0);
    }

#pragma unroll
    for (int mi = 0; mi < 4; ++mi) {
#pragma unroll
        for (int r = 0; r < 4; ++r) {
            int row = m0 + wm * 64 + mi * 16 + quad * 4 + r;
            if (row < M) {
                float s = rsqrtf((float)deg[row] + 1.0f);
#pragma unroll
                for (int ni = 0; ni < 4; ++ni) {
                    int c = n0 + wn * 64 + ni * 16 + l16;
                    out[((size_t)(c >> 5) * (N_NODES + 1) + row) * 32 + (c & 31)] =
                        f2bf(acc[mi][ni][r] * s);
                }
            }
        }
    }
}

// ---------- aggregation v7: tiled + padded CSR + degree-sorted + 16B payloads ----------
// Wave = 16 nodes x 1 tile (tile = blockIdx & 7). 4-lane group owns node perm[k];
// lane loads 16 B (8 bf16 cols). Indices: one uint2 = 4 padded entries (pad -> zero row).
// Degree sort makes wave loop bound ~= mean chunks. No cross-lane reduce.
__global__ __launch_bounds__(256) void agg_kernel(
    const u16* __restrict__ hs, const int* __restrict__ rp4, const u16* __restrict__ col16p,
    const int* __restrict__ deg, const int* __restrict__ perm, const float* __restrict__ bias,
    u16* __restrict__ out_f16, float* __restrict__ out_f, int mode, int Nn) {
    const int wave = threadIdx.x >> 6, lane = threadIdx.x & 63;
    const int t = blockIdx.x & 7;
    const int g = lane >> 2, ql = lane & 3;
    const int k = (blockIdx.x >> 3) * 64 + wave * 16 + g;
    const bool valid = (k < Nn);
    const int i = perm[valid ? k : (Nn - 1)];
    const int cnt = deg[i];
    const int beg4 = rp4[i];
    const int nch = (cnt + 3) >> 2;
    int mch = nch;
    mch = max(mch, __shfl_xor(mch, 4, 64));
    mch = max(mch, __shfl_xor(mch, 8, 64));
    mch = max(mch, __shfl_xor(mch, 16, 64));
    mch = max(mch, __shfl_xor(mch, 32, 64));

    const u16* tb = hs + (size_t)t * (N_NODES + 1) * 32;
    const u32 lqo = (u32)ql * 8;  // u16 elems within 64 B row
    const uint4 vself = *(const uint4*)(tb + ((u32)i << 5) + lqo);

    f32x2 a01 = {0.f, 0.f}, a23 = {0.f, 0.f}, a45 = {0.f, 0.f}, a67 = {0.f, 0.f};

#define PLOAD(e) (*(const uint4*)(tb + ((u32)(e) << 5) + lqo))
#define IADDR(c) (((c) < nch) ? (u32)(beg4 + (c) * 4) : (u32)(PADCAP - 4))
#define ACCUM(v)                                                        \
    {                                                                   \
        f32x2 q0, q1, q2, q3;                                           \
        q0.x = __uint_as_float(v.x << 16);                              \
        q0.y = __uint_as_float(v.x & 0xffff0000u);                      \
        q1.x = __uint_as_float(v.y << 16);                              \
        q1.y = __uint_as_float(v.y & 0xffff0000u);                      \
        q2.x = __uint_as_float(v.z << 16);                              \
        q2.y = __uint_as_float(v.z & 0xffff0000u);                      \
        q3.x = __uint_as_float(v.w << 16);                              \
        q3.y = __uint_as_float(v.w & 0xffff0000u);                      \
        a01 += q0; a23 += q1; a45 += q2; a67 += q3;                     \
    }

    if (mch > 0) {
        uint2 idc = *(const uint2*)(col16p + IADDR(0));
        uint4 p0 = PLOAD(idc.x & 0xffffu), p1 = PLOAD(idc.x >> 16);
        uint4 p2 = PLOAD(idc.y & 0xffffu), p3 = PLOAD(idc.y >> 16);
        uint2 idn = *(const uint2*)(col16p + IADDR(1));
#pragma unroll 2
        for (int c = 0; c < mch; ++c) {
            uint4 q0, q1, q2, q3;
            const bool more = (c + 1 < mch);
            if (more) {
                q0 = PLOAD(idn.x & 0xffffu); q1 = PLOAD(idn.x >> 16);
                q2 = PLOAD(idn.y & 0xffffu); q3 = PLOAD(idn.y >> 16);
                idn = *(const uint2*)(col16p + IADDR(c + 2));
            }
            ACCUM(p0); ACCUM(p1); ACCUM(p2); ACCUM(p3);
            if (more) { p0 = q0; p1 = q1; p2 = q2; p3 = q3; }
        }
    }
    ACCUM(vself);
#undef PLOAD
#undef IADDR
#undef ACCUM

    const float inv = rsqrtf((float)cnt + 1.0f);
    const float4 b0 = *(const float4*)(bias + t * 32 + ql * 8);
    const float4 b1 = *(const float4*)(bias + t * 32 + ql * 8 + 4);
    float r0 = fmaxf(fmaf(a01.x, inv, b0.x), 0.0f);
    float r1 = fmaxf(fmaf(a01.y, inv, b0.y), 0.0f);
    float r2 = fmaxf(fmaf(a23.x, inv, b0.z), 0.0f);
    float r3 = fmaxf(fmaf(a23.y, inv, b0.w), 0.0f);
    float r4 = fmaxf(fmaf(a45.x, inv, b1.x), 0.0f);
    float r5 = fmaxf(fmaf(a45.y, inv, b1.y), 0.0f);
    float r6 = fmaxf(fmaf(a67.x, inv, b1.z), 0.0f);
    float r7 = fmaxf(fmaf(a67.y, inv, b1.w), 0.0f);

    if (valid) {
        const size_t o = (size_t)i * 256 + t * 32 + ql * 8;
        if (mode == 0) {
            uint4 w;
            w.x = (u32)f2h(r0) | ((u32)f2h(r1) << 16);
            w.y = (u32)f2h(r2) | ((u32)f2h(r3) << 16);
            w.z = (u32)f2h(r4) | ((u32)f2h(r5) << 16);
            w.w = (u32)f2h(r6) | ((u32)f2h(r7) << 16);
            *(uint4*)(out_f16 + o) = w;
        } else {
            *(float4*)(out_f + o) = make_float4(r0, r1, r2, r3);
            *(float4*)(out_f + o + 4) = make_float4(r4, r5, r6, r7);
        }
    }
}

extern "C" void kernel_launch(void* const* d_in, const int* in_sizes, int n_in,
                              void* d_out, int out_size, void* d_ws, size_t ws_size,
                              hipStream_t stream) {
    const float* x = (const float*)d_in[0];
    const int* ei = (const int*)d_in[1];
    const float* W1 = (const float*)d_in[2];
    const float* b1 = (const float*)d_in[3];
    const float* W2 = (const float*)d_in[4];
    const float* b2 = (const float*)d_in[5];
    float* out = (float*)d_out;

    const int Nn = N_NODES, E = N_EDGES;
    const int* srcp = ei;
    const int* dstp = ei + E;

    // d_out doubles as scratch: f16 GEMM A buffer (25.6 MB of the 51.2 MB).
    u16* Af = (u16*)d_out;

    char* p = (char*)d_ws;
    auto take = [&](size_t bytes) -> void* {
        void* r = (void*)p;
        p += (bytes + 255) & ~(size_t)255;
        return r;
    };
    u16* hs      = (u16*)take((size_t)8 * (Nn + 1) * 32 * 2);  // tile-major bf16
    u16* col16p  = (u16*)take((size_t)PADCAP * 2);              // padded CSR
    int* deg     = (int*)take((size_t)Nn * 4);
    int* cursor  = (int*)take((size_t)Nn * 4);
    int* rp4     = (int*)take((size_t)Nn * 4);
    int* partial = (int*)take((size_t)NCHUNK * 1024 * 4);
    int* totals  = (int*)take(64 * 4);
    int* hist    = (int*)take(64 * 4);
    int* bincur  = (int*)take(64 * 4);
    int* perm    = (int*)take((size_t)Nn * 4);
    u16* W1t     = (u16*)take(256 * 256 * 2);
    u16* W2t     = (u16*)take(256 * 256 * 2);

    prep_fused<<<SPLIT_BLKS + ZERO_BLKS + W_BLKS + PF_BLKS, 256, 0, stream>>>(
        x, Af, W1, W2, W1t, W2t, deg, hist, (u32*)hs, col16p);
    deg_kernel<<<E / 256, 256, 0, stream>>>(dstp, deg, E);
    hist_kernel<<<ZERO_BLKS, 256, 0, stream>>>(deg, hist, Nn);
    binscan_kernel<<<1, 64, 0, stream>>>(hist, bincur);
    scatter_kernel<<<ZERO_BLKS, 256, 0, stream>>>(deg, bincur, perm, Nn);
    scan1_kernel<<<NCHUNK, 1024, 0, stream>>>(deg, partial, totals, Nn);
    scan3_kernel<<<ZERO_BLKS, 256, 0, stream>>>(deg, partial, totals, rp4, cursor, Nn);
    fill_kernel<<<E / 256, 256, 0, stream>>>(srcp, dstp, cursor, col16p, E);

    const int gm = (Nn + 127) / 128;              // 391
    const int aggblocks = ((Nn + 63) / 64) * 8;   // 782 * 8 = 6256
    // layer 1
    gemm_f16_kernel<<<dim3(gm, 2), 256, 0, stream>>>(Af, W1t, deg, hs, Nn);
    agg_kernel<<<aggblocks, 256, 0, stream>>>(hs, rp4, col16p, deg, perm, b1, Af, nullptr, 0, Nn);
    // layer 2
    gemm_f16_kernel<<<dim3(gm, 2), 256, 0, stream>>>(Af, W2t, deg, hs, Nn);
    agg_kernel<<<aggblocks, 256, 0, stream>>>(hs, rp4, col16p, deg, perm, b2, nullptr, out, 1, Nn);
}

// Round 10
// 405.493 us; speedup vs baseline: 1.5005x; 1.5005x over previous
//
#include <hip/hip_runtime.h>
#include <hip/hip_bf16.h>

typedef unsigned short u16;
typedef unsigned int u32;

#define N_NODES 50000
#define N_EDGES 800000
#define DHID 256
#define NCHUNK 49       // ceil(50000/1024)
#define PADCAP (1 << 20)  // padded CSR capacity (entries); >= E + 3*Nn = 950k
#define NB 196            // node blocks (256 nodes each)

typedef __attribute__((ext_vector_type(8))) _Float16 f16x8;
typedef __attribute__((ext_vector_type(4))) float f32x4;
typedef __attribute__((ext_vector_type(2))) float f32x2;

// ---------- helpers ----------
__device__ __forceinline__ u16 f2bf(float f) {
    u32 u = __float_as_uint(f);
    u32 r = (u + 0x7FFFu + ((u >> 16) & 1u)) >> 16;
    return (u16)r;
}
__device__ __forceinline__ u16 f2h(float f) {
    _Float16 h = (_Float16)f;
    union { _Float16 h; u16 u; } c; c.h = h;
    return c.u;
}
__device__ __forceinline__ void gl_lds16(const void* g, void* l) {
    __builtin_amdgcn_global_load_lds(
        (const __attribute__((address_space(1))) u32*)g,
        (__attribute__((address_space(3))) u32*)l, 16, 0, 0);
}

// ---------- fused prep: x->f16, zero deg/tile-zero-rows, W->W^T f16, pad-fill ----
#define SPLIT_BLKS 12500
#define ZERO_BLKS 196
#define W_BLKS 512
#define PF_BLKS 512  // PADCAP/8 threads / 256
__global__ void prep_fused(const float* __restrict__ x, u16* __restrict__ xf,
                           const float* __restrict__ W1, const float* __restrict__ W2,
                           u16* __restrict__ W1t, u16* __restrict__ W2t,
                           int* __restrict__ deg,
                           u32* __restrict__ hs32, u16* __restrict__ col16p) {
    const int b = blockIdx.x, tid = threadIdx.x;
    if (b < SPLIT_BLKS) {
        int i = b * 256 + tid;  // n4 = 3.2M exact
        float4 v = ((const float4*)x)[i];
        u16 h0 = f2h(v.x), h1 = f2h(v.y), h2 = f2h(v.z), h3 = f2h(v.w);
        uint2 hv;
        hv.x = (u32)h0 | ((u32)h1 << 16);
        hv.y = (u32)h2 | ((u32)h3 << 16);
        ((uint2*)xf)[i] = hv;
    } else if (b < SPLIT_BLKS + ZERO_BLKS) {
        int j = (b - SPLIT_BLKS) * 256 + tid;
        if (j < N_NODES) deg[j] = 0;
        if (j < 128) {  // zero row Nn of each of the 8 tiles (64 B each)
            int t = j >> 4, w = j & 15;
            hs32[((size_t)t * (N_NODES + 1) + N_NODES) * 16 + w] = 0;
        }
    } else if (b < SPLIT_BLKS + ZERO_BLKS + W_BLKS) {
        int idx = b - (SPLIT_BLKS + ZERO_BLKS);  // 0..511
        int y = idx >> 8, n = idx & 255, k = tid;
        const float* W = y ? W2 : W1;
        u16* o = y ? W2t : W1t;
        o[n * 256 + k] = f2h(W[k * 256 + n]);
    } else {
        // pre-fill padded CSR with zero-row index N_NODES (8 entries / thread)
        int j = (b - (SPLIT_BLKS + ZERO_BLKS + W_BLKS)) * 256 + tid;
        const u32 pat = (u32)N_NODES | ((u32)N_NODES << 16);
        uint4 w; w.x = pat; w.y = pat; w.z = pat; w.w = pat;
        ((uint4*)col16p)[j] = w;
    }
}

__global__ void deg_kernel(const int* __restrict__ dst, int* __restrict__ deg, int E) {
    int e = blockIdx.x * 256 + threadIdx.x;
    if (e < E) atomicAdd(&deg[dst[e]], 1);
}

// ---------- counting sort by degree (64 bins) — contention-free ----------
// step 1: per-block LDS histogram -> hist_blk[b][64]
__global__ void histb_kernel(const int* __restrict__ deg, int* __restrict__ hist_blk, int n) {
    __shared__ int lh[64];
    const int tid = threadIdx.x, b = blockIdx.x;
    if (tid < 64) lh[tid] = 0;
    __syncthreads();
    int i = b * 256 + tid;
    if (i < n) atomicAdd(&lh[min(deg[i], 63)], 1);
    __syncthreads();
    if (tid < 64) hist_blk[b * 64 + tid] = lh[tid];
}
// step 2: in-place exclusive offsets: lane=bin scans over blocks, then scan bins
__global__ void binoff_kernel(int* __restrict__ hist_blk, int nb) {
    const int bin = threadIdx.x & 63;
    int run = 0;
    for (int b = 0; b < nb; ++b) {
        int v = hist_blk[b * 64 + bin];
        hist_blk[b * 64 + bin] = run;
        run += v;
    }
    int x = run;
#pragma unroll
    for (int off = 1; off < 64; off <<= 1) {
        int t = __shfl_up(x, off, 64);
        if (bin >= off) x += t;
    }
    const int base = x - run;
    for (int b = 0; b < nb; ++b) hist_blk[b * 64 + bin] += base;
}
// step 3: scatter via LDS cursors (rank within block-bin)
__global__ void scatter2_kernel(const int* __restrict__ deg, const int* __restrict__ hist_blk,
                                int* __restrict__ perm, int n) {
    __shared__ int lh[64];
    const int tid = threadIdx.x, b = blockIdx.x;
    if (tid < 64) lh[tid] = hist_blk[b * 64 + tid];
    __syncthreads();
    int i = b * 256 + tid;
    if (i < n) {
        int pos = atomicAdd(&lh[min(deg[i], 63)], 1);
        perm[pos] = i;
    }
}

// ---------- padded-CSR scans: counts padded to x4 ----------
__global__ __launch_bounds__(1024) void scan1_kernel(const int* __restrict__ deg,
                                                     int* __restrict__ partial,
                                                     int* __restrict__ totals, int n) {
    __shared__ int wsum[16];
    __shared__ int woff[16];
    const int tid = threadIdx.x, lane = tid & 63, wid = tid >> 6;
    const int idx = blockIdx.x * 1024 + tid;
    int v = (idx < n) ? ((deg[idx] + 3) & ~3) : 0;
    int x = v;
#pragma unroll
    for (int off = 1; off < 64; off <<= 1) {
        int t = __shfl_up(x, off, 64);
        if (lane >= off) x += t;
    }
    if (lane == 63) wsum[wid] = x;
    __syncthreads();
    if (tid == 0) {
        int s = 0;
#pragma unroll
        for (int w = 0; w < 16; ++w) { woff[w] = s; s += wsum[w]; }
    }
    __syncthreads();
    x += woff[wid];
    partial[idx] = x;
    if (tid == 1023) totals[blockIdx.x] = x;
}

__global__ void scan3_kernel(const int* __restrict__ deg, const int* __restrict__ partial,
                             const int* __restrict__ totals, int* __restrict__ rp4,
                             int* __restrict__ cursor, int n) {
    __shared__ int coff_s;
    const int tid = threadIdx.x;
    const int mychunk = blockIdx.x >> 2;
    if (tid < 64) {
        int v = (tid < NCHUNK) ? totals[tid] : 0;
        int x = v;
#pragma unroll
        for (int off = 1; off < 64; off <<= 1) {
            int t = __shfl_up(x, off, 64);
            if (tid >= off) x += t;
        }
        if (tid == mychunk) coff_s = x - v;
    }
    __syncthreads();
    int i = blockIdx.x * 256 + tid;
    if (i < n) {
        int pv = (deg[i] + 3) & ~3;
        int e = coff_s + partial[i] - pv;
        rp4[i] = e;
        cursor[i] = e;
    }
}

__global__ void fill_kernel(const int* __restrict__ src, const int* __restrict__ dst,
                            int* __restrict__ cursor, u16* __restrict__ col16p, int E) {
    int e = blockIdx.x * 256 + threadIdx.x;
    if (e < E) {
        int p = atomicAdd(&cursor[dst[e]], 1);
        col16p[p] = (u16)src[e];
    }
}

// ---------- GEMM (f16): hs = (A @ W) * rsqrt(deg[row]+1), bf16 TILE-MAJOR out ----------
__global__ __launch_bounds__(256) void gemm_f16_kernel(
    const u16* __restrict__ Af, const u16* __restrict__ Bt,
    const int* __restrict__ deg, u16* __restrict__ out, int M) {
    __shared__ u16 As[128 * 32];
    __shared__ u16 Bs[128 * 32];
    const int tid = threadIdx.x;
    const int wave = tid >> 6;
    const int lane = tid & 63;
    const int wm = wave >> 1, wn = wave & 1;
    const int quad = lane >> 4, l16 = lane & 15;
    const int m0 = blockIdx.x * 128;
    const int n0 = blockIdx.y * 128;

    f32x4 acc[4][4] = {};

    const int row0 = tid >> 2, row1 = (256 + tid) >> 2;
    const int kk = (tid & 3) * 8;
    int ar0 = m0 + row0; if (ar0 >= M) ar0 = M - 1;
    int ar1 = m0 + row1; if (ar1 >= M) ar1 = M - 1;
    const size_t aoff0 = (size_t)ar0 * 256 + kk;
    const size_t aoff1 = (size_t)ar1 * 256 + kk;
    const size_t boff0 = (size_t)(n0 + row0) * 256 + kk;
    const size_t boff1 = (size_t)(n0 + row1) * 256 + kk;
    const size_t l0 = (size_t)(wave * 64) * 8;
    const size_t l1 = (size_t)(256 + wave * 64) * 8;

    for (int ko = 0; ko < 8; ++ko) {
        const int koff = ko * 32;
        __syncthreads();
        gl_lds16(Af + aoff0 + koff, &As[l0]);
        gl_lds16(Af + aoff1 + koff, &As[l1]);
        gl_lds16(Bt + boff0 + koff, &Bs[l0]);
        gl_lds16(Bt + boff1 + koff, &Bs[l1]);
        asm volatile("s_waitcnt vmcnt(0)" ::: "memory");
        __syncthreads();

        f16x8 af[4], bf[4];
#pragma unroll
        for (int mi = 0; mi < 4; ++mi)
            af[mi] = *(const f16x8*)&As[(wm * 64 + mi * 16 + l16) * 32 + quad * 8];
#pragma unroll
        for (int ni = 0; ni < 4; ++ni)
            bf[ni] = *(const f16x8*)&Bs[(wn * 64 + ni * 16 + l16) * 32 + quad * 8];
#pragma unroll
        for (int mi = 0; mi < 4; ++mi)
#pragma unroll
            for (int ni = 0; ni < 4; ++ni)
                acc[mi][ni] = __builtin_amdgcn_mfma_f32_16x16x32_f16(af[mi], bf[ni], acc[mi][ni], 0, 0, 0);
    }

#pragma unroll
    for (int mi = 0; mi < 4; ++mi) {
#pragma unroll
        for (int r = 0; r < 4; ++r) {
            int row = m0 + wm * 64 + mi * 16 + quad * 4 + r;
            if (row < M) {
                float s = rsqrtf((float)deg[row] + 1.0f);
#pragma unroll
                for (int ni = 0; ni < 4; ++ni) {
                    int c = n0 + wn * 64 + ni * 16 + l16;
                    out[((size_t)(c >> 5) * (N_NODES + 1) + row) * 32 + (c & 31)] =
                        f2bf(acc[mi][ni][r] * s);
                }
            }
        }
    }
}

// ---------- aggregation v7: tiled + padded CSR + degree-sorted + 16B payloads ----------
// Wave = 16 nodes x 1 tile (tile = blockIdx & 7). 4-lane group owns node perm[k];
// lane loads 16 B (8 bf16 cols). Indices: one uint2 = 4 padded entries (pad -> zero row).
// Degree sort makes wave loop bound ~= mean chunks. No cross-lane reduce.
__global__ __launch_bounds__(256) void agg_kernel(
    const u16* __restrict__ hs, const int* __restrict__ rp4, const u16* __restrict__ col16p,
    const int* __restrict__ deg, const int* __restrict__ perm, const float* __restrict__ bias,
    u16* __restrict__ out_f16, float* __restrict__ out_f, int mode, int Nn) {
    const int wave = threadIdx.x >> 6, lane = threadIdx.x & 63;
    const int t = blockIdx.x & 7;
    const int g = lane >> 2, ql = lane & 3;
    const int k = (blockIdx.x >> 3) * 64 + wave * 16 + g;
    const bool valid = (k < Nn);
    const int i = perm[valid ? k : (Nn - 1)];
    const int cnt = deg[i];
    const int beg4 = rp4[i];
    const int nch = (cnt + 3) >> 2;
    int mch = nch;
    mch = max(mch, __shfl_xor(mch, 4, 64));
    mch = max(mch, __shfl_xor(mch, 8, 64));
    mch = max(mch, __shfl_xor(mch, 16, 64));
    mch = max(mch, __shfl_xor(mch, 32, 64));

    const u16* tb = hs + (size_t)t * (N_NODES + 1) * 32;
    const u32 lqo = (u32)ql * 8;  // u16 elems within 64 B row
    const uint4 vself = *(const uint4*)(tb + ((u32)i << 5) + lqo);

    f32x2 a01 = {0.f, 0.f}, a23 = {0.f, 0.f}, a45 = {0.f, 0.f}, a67 = {0.f, 0.f};

#define PLOAD(e) (*(const uint4*)(tb + ((u32)(e) << 5) + lqo))
#define IADDR(c) (((c) < nch) ? (u32)(beg4 + (c) * 4) : (u32)(PADCAP - 4))
#define ACCUM(v)                                                        \
    {                                                                   \
        f32x2 q0, q1, q2, q3;                                           \
        q0.x = __uint_as_float(v.x << 16);                              \
        q0.y = __uint_as_float(v.x & 0xffff0000u);                      \
        q1.x = __uint_as_float(v.y << 16);                              \
        q1.y = __uint_as_float(v.y & 0xffff0000u);                      \
        q2.x = __uint_as_float(v.z << 16);                              \
        q2.y = __uint_as_float(v.z & 0xffff0000u);                      \
        q3.x = __uint_as_float(v.w << 16);                              \
        q3.y = __uint_as_float(v.w & 0xffff0000u);                      \
        a01 += q0; a23 += q1; a45 += q2; a67 += q3;                     \
    }

    if (mch > 0) {
        uint2 idc = *(const uint2*)(col16p + IADDR(0));
        uint4 p0 = PLOAD(idc.x & 0xffffu), p1 = PLOAD(idc.x >> 16);
        uint4 p2 = PLOAD(idc.y & 0xffffu), p3 = PLOAD(idc.y >> 16);
        uint2 idn = *(const uint2*)(col16p + IADDR(1));
#pragma unroll 2
        for (int c = 0; c < mch; ++c) {
            uint4 q0, q1, q2, q3;
            const bool more = (c + 1 < mch);
            if (more) {
                q0 = PLOAD(idn.x & 0xffffu); q1 = PLOAD(idn.x >> 16);
                q2 = PLOAD(idn.y & 0xffffu); q3 = PLOAD(idn.y >> 16);
                idn = *(const uint2*)(col16p + IADDR(c + 2));
            }
            ACCUM(p0); ACCUM(p1); ACCUM(p2); ACCUM(p3);
            if (more) { p0 = q0; p1 = q1; p2 = q2; p3 = q3; }
        }
    }
    ACCUM(vself);
#undef PLOAD
#undef IADDR
#undef ACCUM

    const float inv = rsqrtf((float)cnt + 1.0f);
    const float4 b0 = *(const float4*)(bias + t * 32 + ql * 8);
    const float4 b1 = *(const float4*)(bias + t * 32 + ql * 8 + 4);
    float r0 = fmaxf(fmaf(a01.x, inv, b0.x), 0.0f);
    float r1 = fmaxf(fmaf(a01.y, inv, b0.y), 0.0f);
    float r2 = fmaxf(fmaf(a23.x, inv, b0.z), 0.0f);
    float r3 = fmaxf(fmaf(a23.y, inv, b0.w), 0.0f);
    float r4 = fmaxf(fmaf(a45.x, inv, b1.x), 0.0f);
    float r5 = fmaxf(fmaf(a45.y, inv, b1.y), 0.0f);
    float r6 = fmaxf(fmaf(a67.x, inv, b1.z), 0.0f);
    float r7 = fmaxf(fmaf(a67.y, inv, b1.w), 0.0f);

    if (valid) {
        const size_t o = (size_t)i * 256 + t * 32 + ql * 8;
        if (mode == 0) {
            uint4 w;
            w.x = (u32)f2h(r0) | ((u32)f2h(r1) << 16);
            w.y = (u32)f2h(r2) | ((u32)f2h(r3) << 16);
            w.z = (u32)f2h(r4) | ((u32)f2h(r5) << 16);
            w.w = (u32)f2h(r6) | ((u32)f2h(r7) << 16);
            *(uint4*)(out_f16 + o) = w;
        } else {
            *(float4*)(out_f + o) = make_float4(r0, r1, r2, r3);
            *(float4*)(out_f + o + 4) = make_float4(r4, r5, r6, r7);
        }
    }
}

extern "C" void kernel_launch(void* const* d_in, const int* in_sizes, int n_in,
                              void* d_out, int out_size, void* d_ws, size_t ws_size,
                              hipStream_t stream) {
    const float* x = (const float*)d_in[0];
    const int* ei = (const int*)d_in[1];
    const float* W1 = (const float*)d_in[2];
    const float* b1 = (const float*)d_in[3];
    const float* W2 = (const float*)d_in[4];
    const float* b2 = (const float*)d_in[5];
    float* out = (float*)d_out;

    const int Nn = N_NODES, E = N_EDGES;
    const int* srcp = ei;
    const int* dstp = ei + E;

    // d_out doubles as scratch: f16 GEMM A buffer (25.6 MB of the 51.2 MB).
    u16* Af = (u16*)d_out;

    char* p = (char*)d_ws;
    auto take = [&](size_t bytes) -> void* {
        void* r = (void*)p;
        p += (bytes + 255) & ~(size_t)255;
        return r;
    };
    u16* hs      = (u16*)take((size_t)8 * (Nn + 1) * 32 * 2);  // tile-major bf16
    u16* col16p  = (u16*)take((size_t)PADCAP * 2);              // padded CSR
    int* deg     = (int*)take((size_t)Nn * 4);
    int* cursor  = (int*)take((size_t)Nn * 4);
    int* rp4     = (int*)take((size_t)Nn * 4);
    int* partial = (int*)take((size_t)NCHUNK * 1024 * 4);
    int* totals  = (int*)take(64 * 4);
    int* hist_blk= (int*)take((size_t)NB * 64 * 4);
    int* perm    = (int*)take((size_t)Nn * 4);
    u16* W1t     = (u16*)take(256 * 256 * 2);
    u16* W2t     = (u16*)take(256 * 256 * 2);

    prep_fused<<<SPLIT_BLKS + ZERO_BLKS + W_BLKS + PF_BLKS, 256, 0, stream>>>(
        x, Af, W1, W2, W1t, W2t, deg, (u32*)hs, col16p);
    deg_kernel<<<E / 256, 256, 0, stream>>>(dstp, deg, E);
    histb_kernel<<<NB, 256, 0, stream>>>(deg, hist_blk, Nn);
    binoff_kernel<<<1, 64, 0, stream>>>(hist_blk, NB);
    scatter2_kernel<<<NB, 256, 0, stream>>>(deg, hist_blk, perm, Nn);
    scan1_kernel<<<NCHUNK, 1024, 0, stream>>>(deg, partial, totals, Nn);
    scan3_kernel<<<ZERO_BLKS, 256, 0, stream>>>(deg, partial, totals, rp4, cursor, Nn);
    fill_kernel<<<E / 256, 256, 0, stream>>>(srcp, dstp, cursor, col16p, E);

    const int gm = (Nn + 127) / 128;              // 391
    const int aggblocks = ((Nn + 63) / 64) * 8;   // 782 * 8 = 6256
    // layer 1
    gemm_f16_kernel<<<dim3(gm, 2), 256, 0, stream>>>(Af, W1t, deg, hs, Nn);
    agg_kernel<<<aggblocks, 256, 0, stream>>>(hs, rp4, col16p, deg, perm, b1, Af, nullptr, 0, Nn);
    // layer 2
    gemm_f16_kernel<<<dim3(gm, 2), 256, 0, stream>>>(Af, W2t, deg, hs, Nn);
    agg_kernel<<<aggblocks, 256, 0, stream>>>(hs, rp4, col16p, deg, perm, b2, nullptr, out, 1, Nn);
}